// Round 15
// baseline (46.901 us; speedup 1.0000x reference)
//
#include <hip/hip_runtime.h>
#include <hip/hip_bf16.h>

#define T_STEPS 128
#define BATCH   2048
#define IN_F    64
#define HID     256
#define OUT_F   16
#define CH      8                  // timesteps per chunk
#define NCH     (T_STEPS / CH)     // 16 chunks
#define SLAB    (BATCH * OUT_F)
#define SPART_OFS (32u * 1024u * 1024u)   // spike partials offset in d_ws

typedef __attribute__((ext_vector_type(8))) short bf16x8;
typedef __attribute__((ext_vector_type(4))) float f32x4;
typedef unsigned short u16;
typedef unsigned int   u32;

__device__ __forceinline__ u16 f2bf(float f) {
    union { __hip_bfloat16 h; u16 u; } cv;
    cv.h = __float2bfloat16(f);
    return cv.u;
}
__device__ __forceinline__ float bf2f(u16 h) {
    return __uint_as_float(((u32)h) << 16);
}
__device__ __forceinline__ bf16x8 pack8(float4 a, float4 b) {
    bf16x8 r;
    r[0] = (short)f2bf(a.x); r[1] = (short)f2bf(a.y);
    r[2] = (short)f2bf(a.z); r[3] = (short)f2bf(a.w);
    r[4] = (short)f2bf(b.x); r[5] = (short)f2bf(b.y);
    r[6] = (short)f2bf(b.z); r[7] = (short)f2bf(b.w);
    return r;
}

// LDS-only barrier: drains lgkmcnt but NOT vmcnt.
__device__ __forceinline__ void lds_barrier() {
    __builtin_amdgcn_sched_barrier(0);
    asm volatile("s_waitcnt lgkmcnt(0)" ::: "memory");
    __builtin_amdgcn_sched_barrier(0);
    __builtin_amdgcn_s_barrier();
    __builtin_amdgcn_sched_barrier(0);
}

// Kernel 1: producer/consumer specialization. Block = 16 rows x 128 hid,
// 8 waves. Producers (wv 0-3) own 32 hid each: pure LDS+VALU LIF, two
// independent LIF chains, deferred z-writes. Consumers (wv 4-7): x prefetch
// + staging + full-K g2 MFMA for 2 steps/chunk + slab stores (all global
// traffic lives here; vmcnt never drains at barriers). One lgkm-only
// barrier per window; both role paths execute identical barrier counts.
__global__ void __launch_bounds__(512, 2)
snn_l1_kernel(const float* __restrict__ x, const float* __restrict__ w1,
              const float* __restrict__ w2, u16* __restrict__ g2p,
              u32* __restrict__ spart)
{
    const int tid  = threadIdx.x;
    const int lane = tid & 63;
    const int wv   = tid >> 6;
    const int hi   = lane >> 4;
    const int l15  = lane & 15;
    const int tile = blockIdx.x & 127;       // halves of a tile: same XCD
    const int half = blockIdx.x >> 7;
    const int row0 = tile * 16;

    __shared__ __attribute__((aligned(16))) u16 xl[2][CH * 2 * 512];   // 32 KB
    __shared__ __attribute__((aligned(16))) u16 zb[2][CH * 4 * 512];   // 64 KB

    const f32x4 zf = {0.f, 0.f, 0.f, 0.f};
    const float dt_tau = (float)(0.001 * (1.0 / 0.006));       // 1/6
    const float decay  = (float)(1.0 - 0.001 * (1.0 / 0.006)); // 5/6
    const size_t cstride = (size_t)CH * BATCH * IN_F;

    // Window c (0..NCH): producers run A(c) [c<NCH] on xl[c&1] -> zb[c&1];
    // consumers stage chunk c+1 -> xl[(c+1)&1], issue loads c+2, run C(c-1)
    // on zb[(c-1)&1]. Disjoint buffers within every window; one barrier ends
    // each window. zb[cb]: written A(c), read C in window c+1, rewritten
    // A(c+2) -- reads drained by the barrier ending window c+1. xl[(c+1)&1]:
    // staged window c, read A(c+1), restaged window c+2.

    if (wv < 4) {
        // ------------------------- producer -------------------------
        const int p = wv;                    // owns hid [32p, 32p+32) of half
        bf16x8 w1f[2][2];                    // [tile tau][k-half]
#pragma unroll
        for (int tau = 0; tau < 2; ++tau)
#pragma unroll
            for (int kh = 0; kh < 2; ++kh) {
                const int col = half * 128 + p * 32 + tau * 16 + l15;
                const float* src = &w1[col * IN_F + kh * 32 + hi * 8];
                w1f[tau][kh] = pack8(*(const float4*)src, *(const float4*)(src + 4));
            }
        // z-write offsets: virtual 16-hid wave index w' = 2p+tau (same
        // verified R12-R14 swizzle formula)
        const int zwkey = ((l15 >> 3) << 5) | (((hi >> 1) & 1) << 4);
        int zwofs[2];
#pragma unroll
        for (int tau = 0; tau < 2; ++tau) {
            const int w = 2 * p + tau;
            zwofs[tau] = (w >> 1) * 512
                       + (((((w & 1) * 2 + (hi >> 1)) * 16 + l15) * 8 + (hi & 1) * 4)
                          ^ zwkey);
        }
        f32x4 v1a = zf, i1a = zf, v1b = zf, i1b = zf;
        int wcnt = 0;

        lds_barrier();                       // pairs with consumer prologue bar
        for (int c = 0; c <= NCH; ++c) {
            if (c < NCH) {
                const int kb = c & 1;
                const u16* xb = &xl[kb][0];
                u16* zw = &zb[kb][0];
                bf16x8 xfa[CH], xfb[CH];
#pragma unroll
                for (int s = 0; s < 3; ++s) {
                    xfa[s] = *(const bf16x8*)&xb[(s * 2 + 0) * 512 + lane * 8];
                    xfb[s] = *(const bf16x8*)&xb[(s * 2 + 1) * 512 + lane * 8];
                }
                uint2 zia[CH], zib[CH];
#pragma unroll
                for (int s = 0; s < CH; ++s) {
                    if (s + 3 < CH) {        // dist-3 pipelined reads
                        xfa[s + 3] = *(const bf16x8*)&xb[((s + 3) * 2 + 0) * 512 + lane * 8];
                        xfb[s + 3] = *(const bf16x8*)&xb[((s + 3) * 2 + 1) * 512 + lane * 8];
                    }
                    // two independent 16-hid tiles off one x read
                    f32x4 ga = __builtin_amdgcn_mfma_f32_16x16x32_bf16(w1f[0][0], xfa[s], zf, 0, 0, 0);
                    ga = __builtin_amdgcn_mfma_f32_16x16x32_bf16(w1f[0][1], xfb[s], ga, 0, 0, 0);
                    f32x4 gb = __builtin_amdgcn_mfma_f32_16x16x32_bf16(w1f[1][0], xfa[s], zf, 0, 0, 0);
                    gb = __builtin_amdgcn_mfma_f32_16x16x32_bf16(w1f[1][1], xfb[s], gb, 0, 0, 0);

                    {   // LIF tile a
                        const f32x4 vd = v1a + dt_tau * (i1a - v1a);
                        bool sp[4];
#pragma unroll
                        for (int r = 0; r < 4; ++r) {
                            sp[r] = vd[r] > 1.0f;
                            v1a[r] = sp[r] ? 0.f : vd[r];
                            wcnt += __popcll(__ballot(sp[r]));
                        }
                        i1a = i1a * decay + ga;
                        zia[s].x = (sp[0] ? 0x3F80u : 0u) | (sp[1] ? 0x3F800000u : 0u);
                        zia[s].y = (sp[2] ? 0x3F80u : 0u) | (sp[3] ? 0x3F800000u : 0u);
                    }
                    {   // LIF tile b (independent chain -> ILP)
                        const f32x4 vd = v1b + dt_tau * (i1b - v1b);
                        bool sp[4];
#pragma unroll
                        for (int r = 0; r < 4; ++r) {
                            sp[r] = vd[r] > 1.0f;
                            v1b[r] = sp[r] ? 0.f : vd[r];
                            wcnt += __popcll(__ballot(sp[r]));
                        }
                        i1b = i1b * decay + gb;
                        zib[s].x = (sp[0] ? 0x3F80u : 0u) | (sp[1] ? 0x3F800000u : 0u);
                        zib[s].y = (sp[2] ? 0x3F80u : 0u) | (sp[3] ? 0x3F800000u : 0u);
                    }
                }
                // deferred z-writes (drained by the window-ending barrier)
#pragma unroll
                for (int s = 0; s < CH; ++s) {
                    *(uint2*)&zw[s * 2048 + zwofs[0]] = zia[s];
                    *(uint2*)&zw[s * 2048 + zwofs[1]] = zib[s];
                }
            }
            lds_barrier();
        }
        if (lane == 0) spart[blockIdx.x * 4 + p] = (u32)wcnt;
    } else {
        // ------------------------- consumer -------------------------
        const int q = wv - 4;                // owns steps {2q, 2q+1} per chunk
        bf16x8 w2f[4];                       // full local K=128
#pragma unroll
        for (int kt = 0; kt < 4; ++kt) {
            const int k0 = half * 128 + kt * 32 + hi * 8;
            w2f[kt] = pack8(*(const float4*)&w2[l15 * HID + k0],
                            *(const float4*)&w2[l15 * HID + k0 + 4]);
        }
        const int zrkey = ((l15 >> 3) << 5) | ((hi & 1) << 4);
        const int zrofs = ((hi * 16 + l15) * 8) ^ zrkey;

        // staging map: 1024 16B-units per chunk over 256 consumer threads
        const int ct = tid - 256;
        const float* gp[4];
        int wofs[4];
#pragma unroll
        for (int j = 0; j < 4; ++j) {
            const int u  = ct + 256 * j;
            const int s  = u >> 7, r7 = u & 127;
            const int f  = r7 >> 6, chi = (r7 >> 4) & 3, cl = r7 & 15;
            wofs[j] = (s * 2 + f) * 512 + (chi * 16 + cl) * 8;
            gp[j]   = x + ((size_t)s * BATCH + row0 + cl) * IN_F + f * 32 + chi * 8;
        }
        float4 ra[4], rb[4];
#pragma unroll
        for (int j = 0; j < 4; ++j) {        // chunk 0 -> LDS
            ra[j] = *(const float4*)gp[j];
            rb[j] = *(const float4*)(gp[j] + 4);
            *(bf16x8*)&xl[0][wofs[j]] = pack8(ra[j], rb[j]);
        }
#pragma unroll
        for (int j = 0; j < 4; ++j) {        // chunk 1 -> regs
            ra[j] = *(const float4*)(gp[j] + cstride);
            rb[j] = *(const float4*)(gp[j] + cstride + 4);
            gp[j] += 2 * cstride;
        }

        lds_barrier();                       // prologue staging visible
        for (int c = 0; c <= NCH; ++c) {
            if (c + 1 < NCH) {               // stage chunk c+1
#pragma unroll
                for (int j = 0; j < 4; ++j)
                    *(bf16x8*)&xl[(c + 1) & 1][wofs[j]] = pack8(ra[j], rb[j]);
            }
            if (c + 2 < NCH) {               // issue loads for chunk c+2
#pragma unroll
                for (int j = 0; j < 4; ++j) {
                    ra[j] = *(const float4*)gp[j];
                    rb[j] = *(const float4*)(gp[j] + 4);
                    gp[j] += cstride;
                }
            }
            if (c >= 1) {                    // C(c-1): g2 for steps 2q, 2q+1
                const int cb = (c - 1) & 1;
#pragma unroll
                for (int e = 0; e < 2; ++e) {
                    const int s = q * 2 + e;
                    const u16* zr = &zb[cb][s * 2048];
                    const bf16x8 z0 = *(const bf16x8*)&zr[0 * 512 + zrofs];
                    const bf16x8 z1 = *(const bf16x8*)&zr[1 * 512 + zrofs];
                    const bf16x8 z2 = *(const bf16x8*)&zr[2 * 512 + zrofs];
                    const bf16x8 z3 = *(const bf16x8*)&zr[3 * 512 + zrofs];
                    __builtin_amdgcn_s_setprio(1);
                    f32x4 ga = __builtin_amdgcn_mfma_f32_16x16x32_bf16(z0, w2f[0], zf, 0, 0, 0);
                    f32x4 gb = __builtin_amdgcn_mfma_f32_16x16x32_bf16(z1, w2f[1], zf, 0, 0, 0);
                    ga = __builtin_amdgcn_mfma_f32_16x16x32_bf16(z2, w2f[2], ga, 0, 0, 0);
                    gb = __builtin_amdgcn_mfma_f32_16x16x32_bf16(z3, w2f[3], gb, 0, 0, 0);
                    __builtin_amdgcn_s_setprio(0);
                    const f32x4 g2 = ga + gb;
                    const int t = (c - 1) * CH + s;
                    u16* dst = g2p + (size_t)half * (T_STEPS * SLAB)
                             + (size_t)t * SLAB + (row0 + 4 * hi) * OUT_F + l15;
#pragma unroll
                    for (int r = 0; r < 4; ++r) dst[r * OUT_F] = f2bf(g2[r]);
                }
            }
            lds_barrier();
        }
    }
}

// Kernel 2: LI recurrence + max over t (one thread per (row,out) chain,
// summing the 2 half-slabs); block 0 reduces the 1024 spike partials.
__global__ void __launch_bounds__(256)
snn_li_kernel(const u16* __restrict__ g2p, const u32* __restrict__ spart,
              float* __restrict__ out)
{
    const int gid = blockIdx.x * 256 + threadIdx.x;    // 0..32767
    const u16* p0 = g2p + gid;
    const u16* p1 = p0 + (size_t)T_STEPS * SLAB;
    const float dt_tau = (float)(0.001 * (1.0 / 0.006));
    const float decay  = (float)(1.0 - 0.001 * (1.0 / 0.006));
    float v2 = 0.f, i2 = 0.f, ymax = -1e30f;
#pragma unroll 8
    for (int t = 0; t < T_STEPS; ++t) {
        const size_t o = (size_t)t * SLAB;
        const float g = bf2f(p0[o]) + bf2f(p1[o]);
        v2 = fmaf(dt_tau, i2 - v2, v2);   // uses old i2, matches reference
        ymax = fmaxf(ymax, v2);
        i2 = i2 * decay + g;
    }
    out[gid] = ymax;

    if (blockIdx.x == 0) {
        u32 s = 0;
#pragma unroll
        for (int i = 0; i < 4; ++i) s += spart[threadIdx.x * 4 + i];
#pragma unroll
        for (int m = 1; m < 64; m <<= 1) s += __shfl_xor(s, m, 64);
        __shared__ u32 sb[4];
        if ((threadIdx.x & 63) == 0) sb[threadIdx.x >> 6] = s;
        __syncthreads();
        if (threadIdx.x == 0)
            out[BATCH * OUT_F] =
                (float)(sb[0] + sb[1] + sb[2] + sb[3]) * (1.0f / BATCH);
    }
}

extern "C" void kernel_launch(void* const* d_in, const int* in_sizes, int n_in,
                              void* d_out, int out_size, void* d_ws, size_t ws_size,
                              hipStream_t stream) {
    const float* x  = (const float*)d_in[0];
    const float* w1 = (const float*)d_in[1];
    const float* w2 = (const float*)d_in[2];
    float* out = (float*)d_out;
    u16* g2p   = (u16*)d_ws;
    u32* spart = (u32*)((char*)d_ws + SPART_OFS);    // 1024 u32 partials

    hipLaunchKernelGGL(snn_l1_kernel, dim3(256), dim3(512), 0, stream,
                       x, w1, w2, g2p, spart);
    hipLaunchKernelGGL(snn_li_kernel, dim3(BATCH * OUT_F / 256), dim3(256), 0,
                       stream, g2p, spart, out);
}